// Round 2
// baseline (133.194 us; speedup 1.0000x reference)
//
#include <hip/hip_runtime.h>
#include <math.h>

// Problem constants
#define PB 2048          // P (sequence length)
// ws layout (float offsets), all [b][chan][p] transposed for coalescing
#define OFF_ENC 0        // enc_t (phi output): [4][32][2048]
#define OFF_Q   262144   // q = psi@V : [4][4][2048]
#define OFF_R   294912   // r = comb@U + c : [4][4][2048]
#define OFF_MSK 327680   // mask: [4][2048]
#define OFF_WV  335872   // wv: [16][33][2048] (scan of w, w*enc)

// sW layout (floats). Layer-1 rows padded 33->36 so (i*36 + jb) is 16B-aligned
// for float4 (ds_read_b128) loads; jb in {0,8,16,24}.
#define S_PSI_W1 0       // [31][36]
#define S_PSI_B1 1116    // [32]
#define S_PSI_W2 1148    // [32][32]
#define S_PSI_B2 2172    // [32]
#define S_PHI_W1 2204    // [31][36]
#define S_PHI_B1 3320    // [32]
#define S_PHI_W2 3352    // [32][32]
#define S_PHI_B2 4376    // [32]
#define S_TOT    4408

// ---------------------------------------------------------------------------
// K1: per-position encode, 4 lanes per position (quarters exchange h1 via
// two __shfl_xor rounds at distances 16 and 32 -- all within one wave64).
//   combined(31) -> phi MLP -> enc_t
//   combined(31) -> psi MLP -> q = psi2 @ V   (V = arho_w @ U2, folded here)
//   r = comb @ U[0:31] + arho_b @ U2          (U = fold(W_k,W_q)/sqrt(DOT))
// Linearity: cumsum(psi)@V == cumsum(psi@V), so only 4 scan channels remain.
// LDS reads vectorized: weight row-slices for a lane's 8 outputs are
// contiguous -> 2x ds_read_b128 per row instead of 8 ds_read_b32 (~4x fewer
// LDS instructions; same-addr broadcast within each quarter, conflict-free).
// Accumulation order per output j unchanged -> bit-identical numerics.
__global__ __launch_bounds__(64) void k_encode(
    const float* __restrict__ times, const float* __restrict__ vals,
    const int* __restrict__ meas, const float* __restrict__ mask,
    const float* __restrict__ psi_w1, const float* __restrict__ psi_b1,
    const float* __restrict__ psi_w2, const float* __restrict__ psi_b2,
    const float* __restrict__ phi_w1, const float* __restrict__ phi_b1,
    const float* __restrict__ phi_w2, const float* __restrict__ phi_b2,
    const float* __restrict__ arho_w, const float* __restrict__ arho_b,
    const float* __restrict__ W_k, const float* __restrict__ W_q,
    float* __restrict__ ws)
{
    __shared__ __align__(16) float sW[S_TOT];
    __shared__ float sU[31*4];    // combined-part columns of folded key matrix
    __shared__ float sU2[32*4];   // agg-part columns (temp)
    __shared__ __align__(16) float sV[32*4];   // arho_w @ U2
    __shared__ float sCc[4];      // arho_b @ U2

    // ---- stage weights ----
    for (int i = threadIdx.x; i < 1116; i += 64) {   // 31*36
        int r = i / 36, cc = i - r * 36;
        sW[S_PSI_W1 + i] = (cc < 32) ? psi_w1[r*32 + cc] : 0.0f;
        sW[S_PHI_W1 + i] = (cc < 32) ? phi_w1[r*32 + cc] : 0.0f;
    }
    {
        const float4* p4 = (const float4*)psi_w2;
        const float4* f4 = (const float4*)phi_w2;
        float4* s1 = (float4*)&sW[S_PSI_W2];
        float4* s2 = (float4*)&sW[S_PHI_W2];
        for (int i = threadIdx.x; i < 256; i += 64) { s1[i] = p4[i]; s2[i] = f4[i]; }
    }
    if (threadIdx.x < 32) {
        int i = threadIdx.x;
        sW[S_PSI_B1 + i] = psi_b1[i];
        sW[S_PSI_B2 + i] = psi_b2[i];
        sW[S_PHI_B1 + i] = phi_b1[i];
        sW[S_PHI_B2 + i] = phi_b2[i];
    }
    for (int t = threadIdx.x; t < 252; t += 64) {
        int i = t >> 2, h = t & 3;
        float s = 0.0f;
        #pragma unroll
        for (int d = 0; d < 16; d++)
            s = fmaf(W_k[i*64 + d*4 + h], W_q[h*16 + d], s);
        s *= 0.25f;   // 1/sqrt(16)
        if (i < 31) sU[i*4 + h] = s; else sU2[(i-31)*4 + h] = s;
    }
    __syncthreads();
    for (int t = threadIdx.x; t < 128; t += 64) {
        int ch = t >> 2, h = t & 3;
        float s = 0.0f;
        #pragma unroll
        for (int j = 0; j < 32; j++)
            s = fmaf(arho_w[ch*32 + j], sU2[j*4 + h], s);
        sV[t] = s;
    }
    if (threadIdx.x < 4) {
        float s = 0.0f;
        #pragma unroll
        for (int j = 0; j < 32; j++)
            s = fmaf(arho_b[j], sU2[j*4 + threadIdx.x], s);
        sCc[threadIdx.x] = s;
    }
    __syncthreads();

    const int tid  = threadIdx.x;
    const int qd   = tid >> 4;              // quarter 0..3: j in [qd*8, qd*8+8)
    const int jb   = qd << 3;               // own output base
    const int pp = blockIdx.x * 16 + (tid & 15);
    const int b = pp >> 11, p = pp & 2047;
    const float t = times[pp];
    const float v = vals[pp];
    const float msk = mask[pp];
    const int m = meas[pp];

    float c[9];
    c[0] = sinf(t);           c[1] = cosf(t);
    c[2] = sinf(t * 0.1f);    c[3] = cosf(t * 0.1f);
    c[4] = sinf(t * 0.01f);   c[5] = cosf(t * 0.01f);
    c[6] = sinf(t * 0.001f);  c[7] = cosf(t * 0.001f);
    c[8] = v;

    float* enc_t = ws + OFF_ENC;
    const int cb = b * 32;

    float x[9];
    #pragma unroll
    for (int i = 0; i < 9; i++) x[i] = c[i] * msk;
    const float ohs = (m > 0) ? msk : 0.0f;
    const int   ohr = (m > 0) ? (8 + m) * 36 : 0;   // padded stride

    // ---- r = comb @ U + arho_b@U2 (combined raw/unmasked, per reference) --
    if (qd == 0) {
        float r[4] = {sCc[0], sCc[1], sCc[2], sCc[3]};
        #pragma unroll
        for (int i = 0; i < 9; i++) {
            #pragma unroll
            for (int h = 0; h < 4; h++) r[h] = fmaf(c[i], sU[i*4 + h], r[h]);
        }
        if (m > 0) {
            #pragma unroll
            for (int h = 0; h < 4; h++) r[h] += sU[(8 + m)*4 + h];
        }
        #pragma unroll
        for (int h = 0; h < 4; h++)
            ws[OFF_R + (size_t)(b*4 + h) * PB + p] = r[h];
        ws[OFF_MSK + (size_t)b * PB + p] = msk;
    }

    const bool hi1 = (qd & 1) != 0;   // upper 8 of its 16-chunk
    const bool hi2 = (qd >> 1) != 0;  // upper 16-chunk (j 16..31)

    // ---- psi MLP -> q ----
    {
        float acc[8];
        {
            const float4 b0 = *(const float4*)&sW[S_PSI_B1 + jb];
            const float4 b1 = *(const float4*)&sW[S_PSI_B1 + jb + 4];
            acc[0]=b0.x; acc[1]=b0.y; acc[2]=b0.z; acc[3]=b0.w;
            acc[4]=b1.x; acc[5]=b1.y; acc[6]=b1.z; acc[7]=b1.w;
        }
        #pragma unroll
        for (int i = 0; i < 9; i++) {
            const float4 w0 = *(const float4*)&sW[S_PSI_W1 + i*36 + jb];
            const float4 w1 = *(const float4*)&sW[S_PSI_W1 + i*36 + jb + 4];
            const float xv = x[i];
            acc[0]=fmaf(xv,w0.x,acc[0]); acc[1]=fmaf(xv,w0.y,acc[1]);
            acc[2]=fmaf(xv,w0.z,acc[2]); acc[3]=fmaf(xv,w0.w,acc[3]);
            acc[4]=fmaf(xv,w1.x,acc[4]); acc[5]=fmaf(xv,w1.y,acc[5]);
            acc[6]=fmaf(xv,w1.z,acc[6]); acc[7]=fmaf(xv,w1.w,acc[7]);
        }
        {
            const float4 w0 = *(const float4*)&sW[S_PSI_W1 + ohr + jb];
            const float4 w1 = *(const float4*)&sW[S_PSI_W1 + ohr + jb + 4];
            acc[0]=fmaf(ohs,w0.x,acc[0]); acc[1]=fmaf(ohs,w0.y,acc[1]);
            acc[2]=fmaf(ohs,w0.z,acc[2]); acc[3]=fmaf(ohs,w0.w,acc[3]);
            acc[4]=fmaf(ohs,w1.x,acc[4]); acc[5]=fmaf(ohs,w1.y,acc[5]);
            acc[6]=fmaf(ohs,w1.z,acc[6]); acc[7]=fmaf(ohs,w1.w,acc[7]);
        }
        float h1o[8];
        #pragma unroll
        for (int jj = 0; jj < 8; jj++) h1o[jj] = fmaxf(acc[jj], 0.0f) * msk;

        float hA[16];
        #pragma unroll
        for (int jj = 0; jj < 8; jj++) {
            const float other = __shfl_xor(h1o[jj], 16);
            hA[jj]     = hi1 ? other   : h1o[jj];
            hA[8 + jj] = hi1 ? h1o[jj] : other;
        }
        float h1f[32];
        #pragma unroll
        for (int jj = 0; jj < 16; jj++) {
            const float other = __shfl_xor(hA[jj], 32);
            h1f[jj]      = hi2 ? other  : hA[jj];
            h1f[16 + jj] = hi2 ? hA[jj] : other;
        }
        float a2[8];
        {
            const float4 b0 = *(const float4*)&sW[S_PSI_B2 + jb];
            const float4 b1 = *(const float4*)&sW[S_PSI_B2 + jb + 4];
            a2[0]=b0.x; a2[1]=b0.y; a2[2]=b0.z; a2[3]=b0.w;
            a2[4]=b1.x; a2[5]=b1.y; a2[6]=b1.z; a2[7]=b1.w;
        }
        #pragma unroll
        for (int i = 0; i < 32; i++) {
            const float4 w0 = *(const float4*)&sW[S_PSI_W2 + i*32 + jb];
            const float4 w1 = *(const float4*)&sW[S_PSI_W2 + i*32 + jb + 4];
            const float hv = h1f[i];
            a2[0]=fmaf(hv,w0.x,a2[0]); a2[1]=fmaf(hv,w0.y,a2[1]);
            a2[2]=fmaf(hv,w0.z,a2[2]); a2[3]=fmaf(hv,w0.w,a2[3]);
            a2[4]=fmaf(hv,w1.x,a2[4]); a2[5]=fmaf(hv,w1.y,a2[5]);
            a2[6]=fmaf(hv,w1.z,a2[6]); a2[7]=fmaf(hv,w1.w,a2[7]);
        }
        float q[4] = {0.f, 0.f, 0.f, 0.f};
        #pragma unroll
        for (int jj = 0; jj < 8; jj++) {
            const float p2 = fmaxf(a2[jj], 0.0f) * msk;
            const float4 vv = *(const float4*)&sV[(jb + jj)*4];
            q[0] = fmaf(p2, vv.x, q[0]);
            q[1] = fmaf(p2, vv.y, q[1]);
            q[2] = fmaf(p2, vv.z, q[2]);
            q[3] = fmaf(p2, vv.w, q[3]);
        }
        #pragma unroll
        for (int h = 0; h < 4; h++) {
            q[h] += __shfl_xor(q[h], 16);
            q[h] += __shfl_xor(q[h], 32);
        }
        if (qd == 0) {
            #pragma unroll
            for (int h = 0; h < 4; h++)
                ws[OFF_Q + (size_t)(b*4 + h) * PB + p] = q[h];
        }
    }
    // ---- phi MLP -> enc_t ----
    {
        float acc[8];
        {
            const float4 b0 = *(const float4*)&sW[S_PHI_B1 + jb];
            const float4 b1 = *(const float4*)&sW[S_PHI_B1 + jb + 4];
            acc[0]=b0.x; acc[1]=b0.y; acc[2]=b0.z; acc[3]=b0.w;
            acc[4]=b1.x; acc[5]=b1.y; acc[6]=b1.z; acc[7]=b1.w;
        }
        #pragma unroll
        for (int i = 0; i < 9; i++) {
            const float4 w0 = *(const float4*)&sW[S_PHI_W1 + i*36 + jb];
            const float4 w1 = *(const float4*)&sW[S_PHI_W1 + i*36 + jb + 4];
            const float xv = x[i];
            acc[0]=fmaf(xv,w0.x,acc[0]); acc[1]=fmaf(xv,w0.y,acc[1]);
            acc[2]=fmaf(xv,w0.z,acc[2]); acc[3]=fmaf(xv,w0.w,acc[3]);
            acc[4]=fmaf(xv,w1.x,acc[4]); acc[5]=fmaf(xv,w1.y,acc[5]);
            acc[6]=fmaf(xv,w1.z,acc[6]); acc[7]=fmaf(xv,w1.w,acc[7]);
        }
        {
            const float4 w0 = *(const float4*)&sW[S_PHI_W1 + ohr + jb];
            const float4 w1 = *(const float4*)&sW[S_PHI_W1 + ohr + jb + 4];
            acc[0]=fmaf(ohs,w0.x,acc[0]); acc[1]=fmaf(ohs,w0.y,acc[1]);
            acc[2]=fmaf(ohs,w0.z,acc[2]); acc[3]=fmaf(ohs,w0.w,acc[3]);
            acc[4]=fmaf(ohs,w1.x,acc[4]); acc[5]=fmaf(ohs,w1.y,acc[5]);
            acc[6]=fmaf(ohs,w1.z,acc[6]); acc[7]=fmaf(ohs,w1.w,acc[7]);
        }
        float h1o[8];
        #pragma unroll
        for (int jj = 0; jj < 8; jj++) h1o[jj] = fmaxf(acc[jj], 0.0f) * msk;

        float hA[16];
        #pragma unroll
        for (int jj = 0; jj < 8; jj++) {
            const float other = __shfl_xor(h1o[jj], 16);
            hA[jj]     = hi1 ? other   : h1o[jj];
            hA[8 + jj] = hi1 ? h1o[jj] : other;
        }
        float h1f[32];
        #pragma unroll
        for (int jj = 0; jj < 16; jj++) {
            const float other = __shfl_xor(hA[jj], 32);
            h1f[jj]      = hi2 ? other  : hA[jj];
            h1f[16 + jj] = hi2 ? hA[jj] : other;
        }
        float a2[8];
        {
            const float4 b0 = *(const float4*)&sW[S_PHI_B2 + jb];
            const float4 b1 = *(const float4*)&sW[S_PHI_B2 + jb + 4];
            a2[0]=b0.x; a2[1]=b0.y; a2[2]=b0.z; a2[3]=b0.w;
            a2[4]=b1.x; a2[5]=b1.y; a2[6]=b1.z; a2[7]=b1.w;
        }
        #pragma unroll
        for (int i = 0; i < 32; i++) {
            const float4 w0 = *(const float4*)&sW[S_PHI_W2 + i*32 + jb];
            const float4 w1 = *(const float4*)&sW[S_PHI_W2 + i*32 + jb + 4];
            const float hv = h1f[i];
            a2[0]=fmaf(hv,w0.x,a2[0]); a2[1]=fmaf(hv,w0.y,a2[1]);
            a2[2]=fmaf(hv,w0.z,a2[2]); a2[3]=fmaf(hv,w0.w,a2[3]);
            a2[4]=fmaf(hv,w1.x,a2[4]); a2[5]=fmaf(hv,w1.y,a2[5]);
            a2[6]=fmaf(hv,w1.z,a2[6]); a2[7]=fmaf(hv,w1.w,a2[7]);
        }
        #pragma unroll
        for (int jj = 0; jj < 8; jj++)
            enc_t[(size_t)(cb + jb + jj) * PB + p] = fmaxf(a2[jj], 0.0f) * msk;
    }
}

// ---------------------------------------------------------------------------
// K2: fused scan+exp+weight-mul+scan. Block = one (bh, c), c in [0,33):
//   cumq = inclusive-scan(q[bh])                       (redundant per c: cheap)
//   ex   = exp(msk * (r[bh] + cumq/(p+1)))
//   v    = (c==0) ? ex : ex * enc[b][c-1]
//   wv[bh][c] = inclusive-scan(v)
__global__ __launch_bounds__(64) void k_mid(float* __restrict__ ws)
{
    const int blk = blockIdx.x;
    const int bh = blk / 33;
    const int c  = blk - bh * 33;
    const int b  = bh >> 2;
    const int lane = threadIdx.x;

    const float4* q4 = (const float4*)(ws + OFF_Q   + (size_t)bh * PB + lane * 32);
    const float4* r4 = (const float4*)(ws + OFF_R   + (size_t)bh * PB + lane * 32);
    const float4* m4 = (const float4*)(ws + OFF_MSK + (size_t)b  * PB + lane * 32);
    const float4* e4 = (const float4*)(ws + OFF_ENC + ((size_t)(b*32 + (c-1))) * PB + lane * 32);
    float4* o4 = (float4*)(ws + OFF_WV + ((size_t)(bh*33 + c)) * PB + lane * 32);

    float vq[32];
    #pragma unroll
    for (int k = 0; k < 8; k++) {
        float4 f = q4[k];
        vq[4*k] = f.x; vq[4*k+1] = f.y; vq[4*k+2] = f.z; vq[4*k+3] = f.w;
    }
    // inclusive scan of q
    #pragma unroll
    for (int j = 1; j < 32; j++) vq[j] += vq[j-1];
    {
        const float tot = vq[31];
        float x = tot;
        #pragma unroll
        for (int off = 1; off < 64; off <<= 1) {
            float y = __shfl_up(x, off);
            if (lane >= off) x += y;
        }
        const float excl = x - tot;
        #pragma unroll
        for (int j = 0; j < 32; j++) vq[j] += excl;
    }
    // ex = exp(msk*(r + cumq/(p+1))), then multiply by enc channel
    float v[32];
    #pragma unroll
    for (int k = 0; k < 8; k++) {
        const float4 fr = r4[k];
        const float4 fm = m4[k];
        const int p0 = lane * 32 + 4*k;
        v[4*k+0] = expf(fm.x * (fr.x + vq[4*k+0] / (float)(p0 + 1)));
        v[4*k+1] = expf(fm.y * (fr.y + vq[4*k+1] / (float)(p0 + 2)));
        v[4*k+2] = expf(fm.z * (fr.z + vq[4*k+2] / (float)(p0 + 3)));
        v[4*k+3] = expf(fm.w * (fr.w + vq[4*k+3] / (float)(p0 + 4)));
    }
    if (c > 0) {
        #pragma unroll
        for (int k = 0; k < 8; k++) {
            float4 f = e4[k];
            v[4*k] *= f.x; v[4*k+1] *= f.y; v[4*k+2] *= f.z; v[4*k+3] *= f.w;
        }
    }
    // inclusive scan of v
    #pragma unroll
    for (int j = 1; j < 32; j++) v[j] += v[j-1];
    const float tot = v[31];
    float x = tot;
    #pragma unroll
    for (int off = 1; off < 64; off <<= 1) {
        float y = __shfl_up(x, off);
        if (lane >= off) x += y;
    }
    const float excl = x - tot;
    #pragma unroll
    for (int j = 0; j < 32; j++) v[j] += excl;
    #pragma unroll
    for (int k = 0; k < 8; k++)
        o4[k] = make_float4(v[4*k], v[4*k+1], v[4*k+2], v[4*k+3]);
}

// ---------------------------------------------------------------------------
// K3: out5 = C/L -> agg2(128) -> rho MLP (128->64->64).
// 512 blocks x 256 threads; block = 16 positions; thread = (pos, 4-output
// group). Weights via coalesced float4 global loads (L1-hot, 48 KB total).
__global__ __launch_bounds__(256) void k_rho(
    const float* __restrict__ rho_w1, const float* __restrict__ rho_b1,
    const float* __restrict__ rho_w2, const float* __restrict__ rho_b2,
    const float* __restrict__ ws, float* __restrict__ out)
{
    __shared__ float h1s[16][65];   // [pos][j], 65 keeps banks spread
    __shared__ float scl[16][4];    // msk/L per (pos,h)
    __shared__ float mskS[16];
    const int tid = threadIdx.x;
    const int pos = tid >> 4;       // 0..15
    const int g   = tid & 15;       // output group of 4
    const int pbase = blockIdx.x * 16;
    const int b  = pbase >> 11;
    const int p0 = pbase & 2047;
    const float* wv = ws + OFF_WV + (size_t)b * 132 * PB;   // 4*33 channels

    if (tid < 64) {
        const int pp = tid >> 2, h = tid & 3;
        const float msk = ws[OFF_MSK + (size_t)b * PB + p0 + pp];
        const float L = wv[(size_t)(h*33) * PB + p0 + pp];
        scl[pp][h] = msk / L;
        if (h == 0) mskS[pp] = msk;
    }
    __syncthreads();

    const int pg = p0 + pos;
    float4 acc = ((const float4*)rho_b1)[g];
    const float4* w14 = (const float4*)rho_w1;
    const float sc0 = scl[pos][0], sc1 = scl[pos][1];
    const float sc2 = scl[pos][2], sc3 = scl[pos][3];
    #pragma unroll
    for (int h = 0; h < 4; h++) {
        const float sc = (h == 0) ? sc0 : (h == 1) ? sc1 : (h == 2) ? sc2 : sc3;
        const float* wvh = wv + (size_t)(h*33 + 1) * PB + pg;
        #pragma unroll 8
        for (int d = 0; d < 32; d++) {
            const float ai = wvh[(size_t)d * PB] * sc;
            const float4 w = w14[(h*32 + d)*16 + g];
            acc.x = fmaf(ai, w.x, acc.x);
            acc.y = fmaf(ai, w.y, acc.y);
            acc.z = fmaf(ai, w.z, acc.z);
            acc.w = fmaf(ai, w.w, acc.w);
        }
    }
    const float msk = mskS[pos];
    h1s[pos][g*4+0] = fmaxf(acc.x, 0.f) * msk;
    h1s[pos][g*4+1] = fmaxf(acc.y, 0.f) * msk;
    h1s[pos][g*4+2] = fmaxf(acc.z, 0.f) * msk;
    h1s[pos][g*4+3] = fmaxf(acc.w, 0.f) * msk;
    __syncthreads();

    float4 acc2 = ((const float4*)rho_b2)[g];
    const float4* w24 = (const float4*)rho_w2;
    #pragma unroll 16
    for (int i = 0; i < 64; i++) {
        const float hv = h1s[pos][i];
        const float4 w = w24[i*16 + g];
        acc2.x = fmaf(hv, w.x, acc2.x);
        acc2.y = fmaf(hv, w.y, acc2.y);
        acc2.z = fmaf(hv, w.z, acc2.z);
        acc2.w = fmaf(hv, w.w, acc2.w);
    }
    float4 o;
    o.x = fmaxf(acc2.x, 0.f) * msk;
    o.y = fmaxf(acc2.y, 0.f) * msk;
    o.z = fmaxf(acc2.z, 0.f) * msk;
    o.w = fmaxf(acc2.w, 0.f) * msk;
    ((float4*)out)[(size_t)(pbase + pos) * 16 + g] = o;   // lane-contiguous
}

// ---------------------------------------------------------------------------
extern "C" void kernel_launch(void* const* d_in, const int* in_sizes, int n_in,
                              void* d_out, int out_size, void* d_ws, size_t ws_size,
                              hipStream_t stream)
{
    const float* times  = (const float*)d_in[0];
    const float* vals   = (const float*)d_in[1];
    const int*   meas   = (const int*)d_in[2];
    const float* mask   = (const float*)d_in[3];
    const float* psi_w1 = (const float*)d_in[4];
    const float* psi_b1 = (const float*)d_in[5];
    const float* psi_w2 = (const float*)d_in[6];
    const float* psi_b2 = (const float*)d_in[7];
    const float* arho_w = (const float*)d_in[8];
    const float* arho_b = (const float*)d_in[9];
    const float* W_k    = (const float*)d_in[10];
    const float* W_q    = (const float*)d_in[11];
    const float* phi_w1 = (const float*)d_in[12];
    const float* phi_b1 = (const float*)d_in[13];
    const float* phi_w2 = (const float*)d_in[14];
    const float* phi_b2 = (const float*)d_in[15];
    const float* rho_w1 = (const float*)d_in[16];
    const float* rho_b1 = (const float*)d_in[17];
    const float* rho_w2 = (const float*)d_in[18];
    const float* rho_b2 = (const float*)d_in[19];
    float* ws  = (float*)d_ws;
    float* out = (float*)d_out;

    k_encode<<<dim3(512), dim3(64), 0, stream>>>(times, vals, meas, mask,
        psi_w1, psi_b1, psi_w2, psi_b2, phi_w1, phi_b1, phi_w2, phi_b2,
        arho_w, arho_b, W_k, W_q, ws);
    k_mid<<<dim3(528), dim3(64), 0, stream>>>(ws);
    k_rho<<<dim3(512), dim3(256), 0, stream>>>(rho_w1, rho_b1, rho_w2, rho_b2, ws, out);
}

// Round 3
// 128.304 us; speedup vs baseline: 1.0381x; 1.0381x over previous
//
#include <hip/hip_runtime.h>
#include <math.h>

// Problem constants
#define PB 2048          // P (sequence length)
// ws layout (float offsets), all [b][chan][p] transposed for coalescing
#define OFF_ENC 0        // enc_t (phi output): [4][32][2048]
#define OFF_Q   262144   // q = psi@V : [4][4][2048]
#define OFF_R   294912   // r = comb@U + c : [4][4][2048]
#define OFF_MSK 327680   // mask: [4][2048]
#define OFF_WV  335872   // wv: [16][33][2048] (scan of w, w*enc)

// sW layout (floats). Layer-1 rows padded 32->36 (36 = 9 float4) so both the
// staging stores and the (i*36 + jb) fragment reads are 16B-aligned.
#define S_PSI_W1 0       // [31][36]
#define S_PSI_B1 1116    // [32]
#define S_PSI_W2 1148    // [32][32]
#define S_PSI_B2 2172    // [32]
#define S_PHI_W1 2204    // [31][36]
#define S_PHI_B1 3320    // [32]
#define S_PHI_W2 3352    // [32][32]
#define S_PHI_B2 4376    // [32]
#define S_TOT    4408

// ---------------------------------------------------------------------------
// K1: per-position encode. 128 threads = 2 waves; 16 positions per block
// (8 per wave), 8 lanes per position, each lane owns 4 MLP outputs.
// h1 (32 wide) gathered via 3 __shfl_xor rounds (dist 8,16,32) in-wave.
//   combined(31) -> phi MLP -> enc_t
//   combined(31) -> psi MLP -> q = psi2 @ V   (V = arho_w @ U2, folded here)
//   r = comb @ U[0:31] + arho_b @ U2          (U = fold(W_k,W_q)/sqrt(DOT))
// Linearity: cumsum(psi)@V == cumsum(psi@V), so only 4 scan channels remain.
// Prologue fully vectorized (float4 staging, float4 W_k fold) and hidden
// across 2 waves; per-output accumulation orders preserved (bit-identical
// MLP numerics; only the 4-way->8-way q head reduction re-associates).
__global__ __launch_bounds__(128) void k_encode(
    const float* __restrict__ times, const float* __restrict__ vals,
    const int* __restrict__ meas, const float* __restrict__ mask,
    const float* __restrict__ psi_w1, const float* __restrict__ psi_b1,
    const float* __restrict__ psi_w2, const float* __restrict__ psi_b2,
    const float* __restrict__ phi_w1, const float* __restrict__ phi_b1,
    const float* __restrict__ phi_w2, const float* __restrict__ phi_b2,
    const float* __restrict__ arho_w, const float* __restrict__ arho_b,
    const float* __restrict__ W_k, const float* __restrict__ W_q,
    float* __restrict__ ws)
{
    __shared__ __align__(16) float sW[S_TOT];
    __shared__ __align__(16) float sU[31*4];    // combined-part cols of folded key matrix
    __shared__ __align__(16) float sU2[32*4];   // agg-part cols (temp)
    __shared__ __align__(16) float sV[32*4];    // arho_w @ U2
    __shared__ __align__(16) float sCc[4];      // arho_b @ U2

    const int tid = threadIdx.x;

    // ---- stage weights (all float4) ----
    {
        const float4* a4 = (const float4*)psi_w1;   // 248 float4 (31x32)
        const float4* b4 = (const float4*)phi_w1;
        float4* d1 = (float4*)&sW[S_PSI_W1];
        float4* d2 = (float4*)&sW[S_PHI_W1];
        for (int i = tid; i < 248; i += 128) {
            const int r = i >> 3, c4 = i & 7;
            d1[r*9 + c4] = a4[i];                   // pad cols 32..35 never read
            d2[r*9 + c4] = b4[i];
        }
    }
    {
        const float4* p4 = (const float4*)psi_w2;   // 256 float4 (32x32)
        const float4* f4 = (const float4*)phi_w2;
        float4* s1 = (float4*)&sW[S_PSI_W2];
        float4* s2 = (float4*)&sW[S_PHI_W2];
        for (int i = tid; i < 256; i += 128) { s1[i] = p4[i]; s2[i] = f4[i]; }
    }
    if (tid < 32) {
        sW[S_PSI_B1 + tid] = psi_b1[tid];
        sW[S_PSI_B2 + tid] = psi_b2[tid];
        sW[S_PHI_B1 + tid] = phi_b1[tid];
        sW[S_PHI_B2 + tid] = phi_b2[tid];
    }
    // ---- fold W_k @ W_q / sqrt(DOT): one row per thread, float4 loads ----
    if (tid < 63) {
        const int i = tid;
        const float4* wk4 = (const float4*)(W_k + i*64);   // row i, 16 float4
        float4 s = make_float4(0.f, 0.f, 0.f, 0.f);
        #pragma unroll
        for (int d = 0; d < 16; d++) {
            const float4 w = wk4[d];
            s.x = fmaf(w.x, W_q[d],      s.x);
            s.y = fmaf(w.y, W_q[16 + d], s.y);
            s.z = fmaf(w.z, W_q[32 + d], s.z);
            s.w = fmaf(w.w, W_q[48 + d], s.w);
        }
        s.x *= 0.25f; s.y *= 0.25f; s.z *= 0.25f; s.w *= 0.25f;   // 1/sqrt(16)
        if (i < 31) *(float4*)&sU[i*4]        = s;
        else        *(float4*)&sU2[(i-31)*4]  = s;
    }
    __syncthreads();
    // ---- sV = arho_w @ U2, sCc = arho_b @ U2 (float4 over heads) ----
    if (tid < 32) {
        const float* aw = arho_w + tid*32;
        float4 s = make_float4(0.f, 0.f, 0.f, 0.f);
        #pragma unroll
        for (int j = 0; j < 32; j++) {
            const float a = aw[j];
            const float4 u = *(const float4*)&sU2[j*4];
            s.x = fmaf(a, u.x, s.x); s.y = fmaf(a, u.y, s.y);
            s.z = fmaf(a, u.z, s.z); s.w = fmaf(a, u.w, s.w);
        }
        *(float4*)&sV[tid*4] = s;
    } else if (tid == 32) {
        float4 s = make_float4(0.f, 0.f, 0.f, 0.f);
        #pragma unroll
        for (int j = 0; j < 32; j++) {
            const float a = arho_b[j];
            const float4 u = *(const float4*)&sU2[j*4];
            s.x = fmaf(a, u.x, s.x); s.y = fmaf(a, u.y, s.y);
            s.z = fmaf(a, u.z, s.z); s.w = fmaf(a, u.w, s.w);
        }
        *(float4*)&sCc[0] = s;
    }
    __syncthreads();

    const int wv_  = tid >> 6;              // wave 0/1
    const int lane = tid & 63;
    const int qd   = lane >> 3;             // 0..7: owns j in [qd*4, qd*4+4)
    const int jb   = qd << 2;
    const int pp = blockIdx.x * 16 + wv_ * 8 + (lane & 7);
    const int b = pp >> 11, p = pp & 2047;
    const float t = times[pp];
    const float v = vals[pp];
    const float msk = mask[pp];
    const int m = meas[pp];

    float c[9];
    c[0] = sinf(t);           c[1] = cosf(t);
    c[2] = sinf(t * 0.1f);    c[3] = cosf(t * 0.1f);
    c[4] = sinf(t * 0.01f);   c[5] = cosf(t * 0.01f);
    c[6] = sinf(t * 0.001f);  c[7] = cosf(t * 0.001f);
    c[8] = v;

    float* enc_t = ws + OFF_ENC;
    const int cb = b * 32;

    float x[9];
    #pragma unroll
    for (int i = 0; i < 9; i++) x[i] = c[i] * msk;
    const float ohs = (m > 0) ? msk : 0.0f;
    const int   ohr = (m > 0) ? (8 + m) * 36 : 0;   // padded stride

    // ---- r = comb @ U + arho_b@U2 (combined raw/unmasked, per reference) --
    if (qd == 0) {
        float4 r = *(const float4*)&sCc[0];
        #pragma unroll
        for (int i = 0; i < 9; i++) {
            const float4 u = *(const float4*)&sU[i*4];
            const float cv = c[i];
            r.x = fmaf(cv, u.x, r.x); r.y = fmaf(cv, u.y, r.y);
            r.z = fmaf(cv, u.z, r.z); r.w = fmaf(cv, u.w, r.w);
        }
        if (m > 0) {
            const float4 u = *(const float4*)&sU[(8 + m)*4];
            r.x += u.x; r.y += u.y; r.z += u.z; r.w += u.w;
        }
        ws[OFF_R + (size_t)(b*4 + 0) * PB + p] = r.x;
        ws[OFF_R + (size_t)(b*4 + 1) * PB + p] = r.y;
        ws[OFF_R + (size_t)(b*4 + 2) * PB + p] = r.z;
        ws[OFF_R + (size_t)(b*4 + 3) * PB + p] = r.w;
        ws[OFF_MSK + (size_t)b * PB + p] = msk;
    }

    const bool hiA = (qd & 1) != 0;
    const bool hiB = (qd & 2) != 0;
    const bool hiC = (qd & 4) != 0;

    // ---- psi MLP -> q ----
    {
        float4 a1 = *(const float4*)&sW[S_PSI_B1 + jb];
        #pragma unroll
        for (int i = 0; i < 9; i++) {
            const float4 w = *(const float4*)&sW[S_PSI_W1 + i*36 + jb];
            const float xv = x[i];
            a1.x = fmaf(xv, w.x, a1.x); a1.y = fmaf(xv, w.y, a1.y);
            a1.z = fmaf(xv, w.z, a1.z); a1.w = fmaf(xv, w.w, a1.w);
        }
        {
            const float4 w = *(const float4*)&sW[S_PSI_W1 + ohr + jb];
            a1.x = fmaf(ohs, w.x, a1.x); a1.y = fmaf(ohs, w.y, a1.y);
            a1.z = fmaf(ohs, w.z, a1.z); a1.w = fmaf(ohs, w.w, a1.w);
        }
        float h1o[4];
        h1o[0] = fmaxf(a1.x, 0.f) * msk; h1o[1] = fmaxf(a1.y, 0.f) * msk;
        h1o[2] = fmaxf(a1.z, 0.f) * msk; h1o[3] = fmaxf(a1.w, 0.f) * msk;

        float hA[8];
        #pragma unroll
        for (int jj = 0; jj < 4; jj++) {
            const float other = __shfl_xor(h1o[jj], 8);
            hA[jj]     = hiA ? other   : h1o[jj];
            hA[4 + jj] = hiA ? h1o[jj] : other;
        }
        float hB[16];
        #pragma unroll
        for (int jj = 0; jj < 8; jj++) {
            const float other = __shfl_xor(hA[jj], 16);
            hB[jj]     = hiB ? other  : hA[jj];
            hB[8 + jj] = hiB ? hA[jj] : other;
        }
        float h1f[32];
        #pragma unroll
        for (int jj = 0; jj < 16; jj++) {
            const float other = __shfl_xor(hB[jj], 32);
            h1f[jj]      = hiC ? other  : hB[jj];
            h1f[16 + jj] = hiC ? hB[jj] : other;
        }
        float4 a2 = *(const float4*)&sW[S_PSI_B2 + jb];
        #pragma unroll
        for (int i = 0; i < 32; i++) {
            const float4 w = *(const float4*)&sW[S_PSI_W2 + i*32 + jb];
            const float hv = h1f[i];
            a2.x = fmaf(hv, w.x, a2.x); a2.y = fmaf(hv, w.y, a2.y);
            a2.z = fmaf(hv, w.z, a2.z); a2.w = fmaf(hv, w.w, a2.w);
        }
        float p2[4];
        p2[0] = fmaxf(a2.x, 0.f) * msk; p2[1] = fmaxf(a2.y, 0.f) * msk;
        p2[2] = fmaxf(a2.z, 0.f) * msk; p2[3] = fmaxf(a2.w, 0.f) * msk;
        float q[4] = {0.f, 0.f, 0.f, 0.f};
        #pragma unroll
        for (int jj = 0; jj < 4; jj++) {
            const float4 vv = *(const float4*)&sV[(jb + jj)*4];
            q[0] = fmaf(p2[jj], vv.x, q[0]);
            q[1] = fmaf(p2[jj], vv.y, q[1]);
            q[2] = fmaf(p2[jj], vv.z, q[2]);
            q[3] = fmaf(p2[jj], vv.w, q[3]);
        }
        #pragma unroll
        for (int h = 0; h < 4; h++) {
            q[h] += __shfl_xor(q[h], 8);
            q[h] += __shfl_xor(q[h], 16);
            q[h] += __shfl_xor(q[h], 32);
        }
        if (qd == 0) {
            #pragma unroll
            for (int h = 0; h < 4; h++)
                ws[OFF_Q + (size_t)(b*4 + h) * PB + p] = q[h];
        }
    }
    // ---- phi MLP -> enc_t ----
    {
        float4 a1 = *(const float4*)&sW[S_PHI_B1 + jb];
        #pragma unroll
        for (int i = 0; i < 9; i++) {
            const float4 w = *(const float4*)&sW[S_PHI_W1 + i*36 + jb];
            const float xv = x[i];
            a1.x = fmaf(xv, w.x, a1.x); a1.y = fmaf(xv, w.y, a1.y);
            a1.z = fmaf(xv, w.z, a1.z); a1.w = fmaf(xv, w.w, a1.w);
        }
        {
            const float4 w = *(const float4*)&sW[S_PHI_W1 + ohr + jb];
            a1.x = fmaf(ohs, w.x, a1.x); a1.y = fmaf(ohs, w.y, a1.y);
            a1.z = fmaf(ohs, w.z, a1.z); a1.w = fmaf(ohs, w.w, a1.w);
        }
        float h1o[4];
        h1o[0] = fmaxf(a1.x, 0.f) * msk; h1o[1] = fmaxf(a1.y, 0.f) * msk;
        h1o[2] = fmaxf(a1.z, 0.f) * msk; h1o[3] = fmaxf(a1.w, 0.f) * msk;

        float hA[8];
        #pragma unroll
        for (int jj = 0; jj < 4; jj++) {
            const float other = __shfl_xor(h1o[jj], 8);
            hA[jj]     = hiA ? other   : h1o[jj];
            hA[4 + jj] = hiA ? h1o[jj] : other;
        }
        float hB[16];
        #pragma unroll
        for (int jj = 0; jj < 8; jj++) {
            const float other = __shfl_xor(hA[jj], 16);
            hB[jj]     = hiB ? other  : hA[jj];
            hB[8 + jj] = hiB ? hA[jj] : other;
        }
        float h1f[32];
        #pragma unroll
        for (int jj = 0; jj < 16; jj++) {
            const float other = __shfl_xor(hB[jj], 32);
            h1f[jj]      = hiC ? other  : hB[jj];
            h1f[16 + jj] = hiC ? hB[jj] : other;
        }
        float4 a2 = *(const float4*)&sW[S_PHI_B2 + jb];
        #pragma unroll
        for (int i = 0; i < 32; i++) {
            const float4 w = *(const float4*)&sW[S_PHI_W2 + i*32 + jb];
            const float hv = h1f[i];
            a2.x = fmaf(hv, w.x, a2.x); a2.y = fmaf(hv, w.y, a2.y);
            a2.z = fmaf(hv, w.z, a2.z); a2.w = fmaf(hv, w.w, a2.w);
        }
        enc_t[(size_t)(cb + jb + 0) * PB + p] = fmaxf(a2.x, 0.f) * msk;
        enc_t[(size_t)(cb + jb + 1) * PB + p] = fmaxf(a2.y, 0.f) * msk;
        enc_t[(size_t)(cb + jb + 2) * PB + p] = fmaxf(a2.z, 0.f) * msk;
        enc_t[(size_t)(cb + jb + 3) * PB + p] = fmaxf(a2.w, 0.f) * msk;
    }
}

// ---------------------------------------------------------------------------
// K2: fused scan+exp+weight-mul+scan. Block = one (bh, c), c in [0,33):
//   cumq = inclusive-scan(q[bh])                       (redundant per c: cheap)
//   ex   = exp(msk * (r[bh] + cumq/(p+1)))
//   v    = (c==0) ? ex : ex * enc[b][c-1]
//   wv[bh][c] = inclusive-scan(v)
__global__ __launch_bounds__(64) void k_mid(float* __restrict__ ws)
{
    const int blk = blockIdx.x;
    const int bh = blk / 33;
    const int c  = blk - bh * 33;
    const int b  = bh >> 2;
    const int lane = threadIdx.x;

    const float4* q4 = (const float4*)(ws + OFF_Q   + (size_t)bh * PB + lane * 32);
    const float4* r4 = (const float4*)(ws + OFF_R   + (size_t)bh * PB + lane * 32);
    const float4* m4 = (const float4*)(ws + OFF_MSK + (size_t)b  * PB + lane * 32);
    const float4* e4 = (const float4*)(ws + OFF_ENC + ((size_t)(b*32 + (c-1))) * PB + lane * 32);
    float4* o4 = (float4*)(ws + OFF_WV + ((size_t)(bh*33 + c)) * PB + lane * 32);

    float vq[32];
    #pragma unroll
    for (int k = 0; k < 8; k++) {
        float4 f = q4[k];
        vq[4*k] = f.x; vq[4*k+1] = f.y; vq[4*k+2] = f.z; vq[4*k+3] = f.w;
    }
    // inclusive scan of q
    #pragma unroll
    for (int j = 1; j < 32; j++) vq[j] += vq[j-1];
    {
        const float tot = vq[31];
        float x = tot;
        #pragma unroll
        for (int off = 1; off < 64; off <<= 1) {
            float y = __shfl_up(x, off);
            if (lane >= off) x += y;
        }
        const float excl = x - tot;
        #pragma unroll
        for (int j = 0; j < 32; j++) vq[j] += excl;
    }
    // ex = exp(msk*(r + cumq/(p+1))), then multiply by enc channel
    float v[32];
    #pragma unroll
    for (int k = 0; k < 8; k++) {
        const float4 fr = r4[k];
        const float4 fm = m4[k];
        const int p0 = lane * 32 + 4*k;
        v[4*k+0] = expf(fm.x * (fr.x + vq[4*k+0] / (float)(p0 + 1)));
        v[4*k+1] = expf(fm.y * (fr.y + vq[4*k+1] / (float)(p0 + 2)));
        v[4*k+2] = expf(fm.z * (fr.z + vq[4*k+2] / (float)(p0 + 3)));
        v[4*k+3] = expf(fm.w * (fr.w + vq[4*k+3] / (float)(p0 + 4)));
    }
    if (c > 0) {
        #pragma unroll
        for (int k = 0; k < 8; k++) {
            float4 f = e4[k];
            v[4*k] *= f.x; v[4*k+1] *= f.y; v[4*k+2] *= f.z; v[4*k+3] *= f.w;
        }
    }
    // inclusive scan of v
    #pragma unroll
    for (int j = 1; j < 32; j++) v[j] += v[j-1];
    const float tot = v[31];
    float x = tot;
    #pragma unroll
    for (int off = 1; off < 64; off <<= 1) {
        float y = __shfl_up(x, off);
        if (lane >= off) x += y;
    }
    const float excl = x - tot;
    #pragma unroll
    for (int j = 0; j < 32; j++) v[j] += excl;
    #pragma unroll
    for (int k = 0; k < 8; k++)
        o4[k] = make_float4(v[4*k], v[4*k+1], v[4*k+2], v[4*k+3]);
}

// ---------------------------------------------------------------------------
// K3: out5 = C/L -> agg2(128) -> rho MLP (128->64->64).
// 512 blocks x 256 threads; block = 16 positions; thread = (pos, 4-output
// group). Weights via coalesced float4 global loads (L1-hot, 48 KB total).
__global__ __launch_bounds__(256) void k_rho(
    const float* __restrict__ rho_w1, const float* __restrict__ rho_b1,
    const float* __restrict__ rho_w2, const float* __restrict__ rho_b2,
    const float* __restrict__ ws, float* __restrict__ out)
{
    __shared__ float h1s[16][65];   // [pos][j], 65 keeps banks spread
    __shared__ float scl[16][4];    // msk/L per (pos,h)
    __shared__ float mskS[16];
    const int tid = threadIdx.x;
    const int pos = tid >> 4;       // 0..15
    const int g   = tid & 15;       // output group of 4
    const int pbase = blockIdx.x * 16;
    const int b  = pbase >> 11;
    const int p0 = pbase & 2047;
    const float* wv = ws + OFF_WV + (size_t)b * 132 * PB;   // 4*33 channels

    if (tid < 64) {
        const int pp = tid >> 2, h = tid & 3;
        const float msk = ws[OFF_MSK + (size_t)b * PB + p0 + pp];
        const float L = wv[(size_t)(h*33) * PB + p0 + pp];
        scl[pp][h] = msk / L;
        if (h == 0) mskS[pp] = msk;
    }
    __syncthreads();

    const int pg = p0 + pos;
    float4 acc = ((const float4*)rho_b1)[g];
    const float4* w14 = (const float4*)rho_w1;
    const float sc0 = scl[pos][0], sc1 = scl[pos][1];
    const float sc2 = scl[pos][2], sc3 = scl[pos][3];
    #pragma unroll
    for (int h = 0; h < 4; h++) {
        const float sc = (h == 0) ? sc0 : (h == 1) ? sc1 : (h == 2) ? sc2 : sc3;
        const float* wvh = wv + (size_t)(h*33 + 1) * PB + pg;
        #pragma unroll 8
        for (int d = 0; d < 32; d++) {
            const float ai = wvh[(size_t)d * PB] * sc;
            const float4 w = w14[(h*32 + d)*16 + g];
            acc.x = fmaf(ai, w.x, acc.x);
            acc.y = fmaf(ai, w.y, acc.y);
            acc.z = fmaf(ai, w.z, acc.z);
            acc.w = fmaf(ai, w.w, acc.w);
        }
    }
    const float msk = mskS[pos];
    h1s[pos][g*4+0] = fmaxf(acc.x, 0.f) * msk;
    h1s[pos][g*4+1] = fmaxf(acc.y, 0.f) * msk;
    h1s[pos][g*4+2] = fmaxf(acc.z, 0.f) * msk;
    h1s[pos][g*4+3] = fmaxf(acc.w, 0.f) * msk;
    __syncthreads();

    float4 acc2 = ((const float4*)rho_b2)[g];
    const float4* w24 = (const float4*)rho_w2;
    #pragma unroll 16
    for (int i = 0; i < 64; i++) {
        const float hv = h1s[pos][i];
        const float4 w = w24[i*16 + g];
        acc2.x = fmaf(hv, w.x, acc2.x);
        acc2.y = fmaf(hv, w.y, acc2.y);
        acc2.z = fmaf(hv, w.z, acc2.z);
        acc2.w = fmaf(hv, w.w, acc2.w);
    }
    float4 o;
    o.x = fmaxf(acc2.x, 0.f) * msk;
    o.y = fmaxf(acc2.y, 0.f) * msk;
    o.z = fmaxf(acc2.z, 0.f) * msk;
    o.w = fmaxf(acc2.w, 0.f) * msk;
    ((float4*)out)[(size_t)(pbase + pos) * 16 + g] = o;   // lane-contiguous
}

// ---------------------------------------------------------------------------
extern "C" void kernel_launch(void* const* d_in, const int* in_sizes, int n_in,
                              void* d_out, int out_size, void* d_ws, size_t ws_size,
                              hipStream_t stream)
{
    const float* times  = (const float*)d_in[0];
    const float* vals   = (const float*)d_in[1];
    const int*   meas   = (const int*)d_in[2];
    const float* mask   = (const float*)d_in[3];
    const float* psi_w1 = (const float*)d_in[4];
    const float* psi_b1 = (const float*)d_in[5];
    const float* psi_w2 = (const float*)d_in[6];
    const float* psi_b2 = (const float*)d_in[7];
    const float* arho_w = (const float*)d_in[8];
    const float* arho_b = (const float*)d_in[9];
    const float* W_k    = (const float*)d_in[10];
    const float* W_q    = (const float*)d_in[11];
    const float* phi_w1 = (const float*)d_in[12];
    const float* phi_b1 = (const float*)d_in[13];
    const float* phi_w2 = (const float*)d_in[14];
    const float* phi_b2 = (const float*)d_in[15];
    const float* rho_w1 = (const float*)d_in[16];
    const float* rho_b1 = (const float*)d_in[17];
    const float* rho_w2 = (const float*)d_in[18];
    const float* rho_b2 = (const float*)d_in[19];
    float* ws  = (float*)d_ws;
    float* out = (float*)d_out;

    k_encode<<<dim3(512), dim3(128), 0, stream>>>(times, vals, meas, mask,
        psi_w1, psi_b1, psi_w2, psi_b2, phi_w1, phi_b1, phi_w2, phi_b2,
        arho_w, arho_b, W_k, W_q, ws);
    k_mid<<<dim3(528), dim3(64), 0, stream>>>(ws);
    k_rho<<<dim3(512), dim3(256), 0, stream>>>(rho_w1, rho_b1, rho_w2, rho_b2, ws, out);
}